// Round 7
// baseline (388.159 us; speedup 1.0000x reference)
//
#include <hip/hip_runtime.h>
#include <hip/hip_bf16.h>

#define HGAT 8
#define DIMGAT 128
#define CAPB 4608          // per-bucket slack capacity (mean 4096, +8 sigma)

typedef __attribute__((ext_vector_type(8))) short short8;
typedef __attribute__((ext_vector_type(4))) float f32x4;

__device__ __forceinline__ float bf16_to_f32(unsigned int u16) {
    return __uint_as_float(u16 << 16);
}
__device__ __forceinline__ unsigned short f32_to_bf16(float x) {
    unsigned int b = __float_as_uint(x);
    b += 0x7FFFu + ((b >> 16) & 1u);   // RNE
    return (unsigned short)(b >> 16);
}

// ---------------- bucketed CSR build ----------------
__global__ void initb_kernel(int* __restrict__ bcursor, int nb) {
    int i = blockIdx.x * blockDim.x + threadIdx.x;
    if (i < nb) bcursor[i] = i * CAPB;
}

// Pass 1: bucket edges by dst>>8. Each workgroup handles 4096 edges: LDS
// histogram -> one global range-reservation atomic per (wg,bucket) -> dense
// packed writes. packed = (src<<8) | (dst&255), src<2^17 fits 25 bits.
__global__ __launch_bounds__(256)
void bucket_scatter(const int* __restrict__ src, const int* __restrict__ dst,
                    int* __restrict__ bcursor, unsigned int* __restrict__ bucket_arr,
                    int e, int nb) {
    __shared__ int lcnt[400];
    __shared__ int lbase[400];
    __shared__ int lrank[400];
    int t = threadIdx.x;
    int e0 = blockIdx.x * 4096;
    for (int i = t; i < nb; i += 256) { lcnt[i] = 0; lrank[i] = 0; }
    __syncthreads();
    int myb[16]; int mys[16];
    #pragma unroll
    for (int q = 0; q < 16; ++q) {
        int i = e0 + q * 256 + t;
        int bb = -1, ss = 0;
        if (i < e) {
            int d = dst[i];
            bb = d >> 8;
            ss = (src[i] << 8) | (d & 255);
        }
        myb[q] = bb; mys[q] = ss;
        if (bb >= 0) atomicAdd(&lcnt[bb], 1);
    }
    __syncthreads();
    for (int i = t; i < nb; i += 256) {
        int c = lcnt[i];
        lbase[i] = c ? atomicAdd(&bcursor[i], c) : 0;
    }
    __syncthreads();
    #pragma unroll
    for (int q = 0; q < 16; ++q) {
        int bb = myb[q];
        if (bb >= 0) {
            int r = atomicAdd(&lrank[bb], 1);
            int pos = lbase[bb] + r;
            if (pos < (bb + 1) * CAPB)      // overflow guard (never in practice)
                bucket_arr[pos] = (unsigned int)mys[q];
        }
    }
}

// Pass 2: one workgroup per bucket. LDS histogram over the bucket's 256 nodes
// (replaces global hist), LDS prefix -> start/deg, then scatter col_src inside
// this bucket's private region (single-XCD dense lines).
__global__ __launch_bounds__(256)
void bucket_finalize(const unsigned int* __restrict__ bucket_arr,
                     const int* __restrict__ bcursor, int* __restrict__ col_src,
                     int* __restrict__ start, int* __restrict__ deg, int n) {
    __shared__ int lcnt[256];
    __shared__ int lcur[256];
    int b = blockIdx.x;
    int t = threadIdx.x;
    int base = b * CAPB;
    int cnt_b = bcursor[b] - base;
    lcnt[t] = 0;
    __syncthreads();
    for (int i = t; i < cnt_b; i += 256)
        atomicAdd(&lcnt[bucket_arr[base + i] & 255u], 1);
    __syncthreads();
    int my = lcnt[t];
    // inclusive Hillis-Steele scan over 256
    for (int off = 1; off < 256; off <<= 1) {
        int v = (t >= off) ? lcnt[t - off] : 0;
        __syncthreads();
        lcnt[t] += v;
        __syncthreads();
    }
    int excl = lcnt[t] - my;
    int node = b * 256 + t;
    if (node < n) {
        start[node] = base + excl;
        deg[node] = my;
    }
    lcur[t] = excl;
    __syncthreads();
    for (int i = t; i < cnt_b; i += 256) {
        unsigned int p = bucket_arr[base + i];
        int r = atomicAdd(&lcur[p & 255u], 1);
        col_src[base + r] = (int)(p >> 8);
    }
}

// ---------------- W pre-convert to fragment-layout bf16 ----------------
// Wb[(ks*8+ct)*64 + lane][j] = bf16( W[(ks*32 + (lane>>4)*8 + j)*128 + ct*16 + (lane&15)] )
__global__ void wcvt_kernel(const float* __restrict__ W, unsigned short* __restrict__ Wb) {
    int t = blockIdx.x * blockDim.x + threadIdx.x;   // 0..2047
    int lane = t & 63;
    int ct = (t >> 6) & 7;
    int ks = t >> 9;
    int lr = lane & 15, lg = lane >> 4;
    const float* wp = W + (ks * 32 + lg * 8) * 128 + ct * 16 + lr;
    unsigned short o[8];
    #pragma unroll
    for (int j = 0; j < 8; ++j) o[j] = f32_to_bf16(wp[j * 128]);
    *(uint4*)(Wb + (size_t)t * 8) = *(const uint4*)o;
}

// ---------------- MFMA GEMM: Cb[n][c] = bf16( sum_k A[n][k] * W[k][c] ), K=N=128 ----
__global__ __launch_bounds__(256)
void gemm_mfma_kernel(const float* __restrict__ A, const unsigned short* __restrict__ Wb,
                      unsigned short* __restrict__ Cb, int nrows) {
    int wave = (int)((blockIdx.x * (size_t)blockDim.x + threadIdx.x) >> 6);
    int nwaves = (int)((gridDim.x * (size_t)blockDim.x) >> 6);
    int lane = threadIdx.x & 63;
    int lr = lane & 15;    // A-row / B-col / D-col within tile
    int lg = lane >> 4;    // k-group

    // W fragments: straight coalesced loads (L2-resident, pre-converted)
    const short8* wb8 = (const short8*)Wb;
    short8 bfrag[4][8];
    #pragma unroll
    for (int ks = 0; ks < 4; ++ks)
        #pragma unroll
        for (int ct = 0; ct < 8; ++ct)
            bfrag[ks][ct] = wb8[(ks * 8 + ct) * 64 + lane];

    int ntiles = nrows >> 4;
    for (int t = wave; t < ntiles; t += nwaves) {
        const float* ap = A + (size_t)(t * 16 + lr) * 128 + lg * 8;
        f32x4 acc[8];
        #pragma unroll
        for (int ct = 0; ct < 8; ++ct) acc[ct] = (f32x4){0.f, 0.f, 0.f, 0.f};
        #pragma unroll
        for (int ks = 0; ks < 4; ++ks) {
            float4 a0 = *(const float4*)(ap + ks * 32);
            float4 a1 = *(const float4*)(ap + ks * 32 + 4);
            short8 af;
            af[0] = (short)f32_to_bf16(a0.x); af[1] = (short)f32_to_bf16(a0.y);
            af[2] = (short)f32_to_bf16(a0.z); af[3] = (short)f32_to_bf16(a0.w);
            af[4] = (short)f32_to_bf16(a1.x); af[5] = (short)f32_to_bf16(a1.y);
            af[6] = (short)f32_to_bf16(a1.z); af[7] = (short)f32_to_bf16(a1.w);
            #pragma unroll
            for (int ct = 0; ct < 8; ++ct)
                acc[ct] = __builtin_amdgcn_mfma_f32_16x16x32_bf16(af, bfrag[ks][ct], acc[ct], 0, 0, 0);
        }
        unsigned short* cp = Cb + (size_t)(t * 16 + lg * 4) * 128 + lr;
        #pragma unroll
        for (int ct = 0; ct < 8; ++ct) {
            #pragma unroll
            for (int r = 0; r < 4; ++r)
                cp[(size_t)r * 128 + ct * 16] = f32_to_bf16(acc[ct][r]);
        }
    }
}

// ---------------- el/er from bf16 feat ----------------
__global__ void elr_kernel(const unsigned short* __restrict__ featb,
                           const float* __restrict__ al, const float* __restrict__ ar,
                           float* __restrict__ el, float* __restrict__ er, int n) {
    int idx = blockIdx.x * blockDim.x + threadIdx.x;   // n*8 + h
    if (idx >= n * HGAT) return;
    int h = idx & 7;
    const uint4* f4 = (const uint4*)(featb + (size_t)idx * 16);
    uint4 va = f4[0], vb = f4[1];
    unsigned int w[8] = {va.x, va.y, va.z, va.w, vb.x, vb.y, vb.z, vb.w};
    const float* a1 = al + h * 16;
    const float* a2 = ar + h * 16;
    float sl = 0.f, sr = 0.f;
    #pragma unroll
    for (int q = 0; q < 8; ++q) {
        float lo = bf16_to_f32(w[q] & 0xFFFFu);
        float hi = bf16_to_f32(w[q] >> 16);
        sl = fmaf(lo, a1[2 * q], fmaf(hi, a1[2 * q + 1], sl));
        sr = fmaf(lo, a2[2 * q], fmaf(hi, a2[2 * q + 1], sr));
    }
    el[idx] = sl;
    er[idx] = sr;
}

// ---------------- per-node aggregation: one wave per dst node ------------------
// 8-edge batches: lane computes exp for ONE (edge j=lane&7, head h=lane>>3) pair
// (kills the 8x redundant exp across each head-group), then (s_j, p_j) are
// broadcast within the 8-lane group via shuffles for the feature accumulation.
__global__ __launch_bounds__(256)
void agg_kernel(const unsigned short* __restrict__ featb, const float* __restrict__ el,
                const float* __restrict__ er, const int* __restrict__ col_src,
                const int* __restrict__ start_arr, const int* __restrict__ deg,
                const float* __restrict__ hin, const float* __restrict__ bias,
                float* __restrict__ out, int n, int applyAct) {
    int wid = (int)((blockIdx.x * (size_t)blockDim.x + threadIdx.x) >> 6);
    if (wid >= n) return;
    int lane = threadIdx.x & 63;
    int h = lane >> 3;              // lane owns feats [2*lane, 2*lane+1] -> head lane>>3
    int jbase = lane & 0x38;        // first lane of my 8-lane group
    int start = start_arr[wid];
    int end = start + deg[wid];
    float er_own = er[wid * 8 + h];

    // single pass: logits bounded, exp safe without max-shift (ratios identical).
    float sum = 0.f, ax = 0.f, ay = 0.f;
    const unsigned int* featw = (const unsigned int*)featb;
    int i = start;
    for (; i + 8 <= end; i += 8) {
        int s_own = col_src[i + (lane & 7)];
        float q = el[s_own * 8 + h] + er_own;
        q = (q >= 0.f) ? q : 0.2f * q;
        float p_own = __expf(q);
        #pragma unroll
        for (int j = 0; j < 8; ++j) {
            int sj   = __shfl(s_own, jbase + j);
            float pj = __shfl(p_own, jbase + j);
            sum += pj;
            unsigned int fw = featw[(size_t)sj * 64 + lane];
            ax = fmaf(pj, bf16_to_f32(fw & 0xFFFFu), ax);
            ay = fmaf(pj, bf16_to_f32(fw >> 16), ay);
        }
    }
    for (; i < end; ++i) {
        int s = col_src[i];
        float e = el[s * 8 + h] + er_own;
        e = (e >= 0.f) ? e : 0.2f * e;
        float p = __expf(e);
        sum += p;
        unsigned int fw = featw[(size_t)s * 64 + lane];
        ax = fmaf(p, bf16_to_f32(fw & 0xFFFFu), ax);
        ay = fmaf(p, bf16_to_f32(fw >> 16), ay);
    }
    float inv = (end > start) ? 1.f / sum : 0.f;
    float2 hv = ((const float2*)hin)[(size_t)wid * 64 + lane];
    float2 bv = ((const float2*)bias)[lane];
    float ox = fmaf(ax, inv, hv.x + bv.x);
    float oy = fmaf(ay, inv, hv.y + bv.y);
    if (applyAct) {
        ox = (ox >= 0.f) ? ox : 0.01f * ox;
        oy = (oy >= 0.f) ? oy : 0.01f * oy;
    }
    ((float2*)out)[(size_t)wid * 64 + lane] = make_float2(ox, oy);
}

// ---------------- launch ----------------
extern "C" void kernel_launch(void* const* d_in, const int* in_sizes, int n_in,
                              void* d_out, int out_size, void* d_ws, size_t ws_size,
                              hipStream_t stream) {
    const float* n_feat = (const float*)d_in[0];
    const int*   src    = (const int*)d_in[1];
    const int*   dst    = (const int*)d_in[2];
    const float* W0  = (const float*)d_in[3];
    const float* al0 = (const float*)d_in[4];
    const float* ar0 = (const float*)d_in[5];
    const float* b0  = (const float*)d_in[6];
    const float* W1  = (const float*)d_in[7];
    const float* al1 = (const float*)d_in[8];
    const float* ar1 = (const float*)d_in[9];
    const float* b1  = (const float*)d_in[10];

    const int n = in_sizes[0] / DIMGAT;   // 100000
    const int e = in_sizes[1];            // 1600000
    const int nb = (n + 255) >> 8;        // 391 buckets

    // workspace layout (256B aligned)
    char* ws = (char*)d_ws;
    size_t off = 0;
    auto alloc = [&](size_t bytes) {
        void* p = ws + off;
        off += (bytes + 255) & ~(size_t)255;
        return p;
    };
    int* bcursor = (int*)alloc((size_t)nb * 4);
    int* start   = (int*)alloc((size_t)n * 4);
    int* deg     = (int*)alloc((size_t)n * 4);
    unsigned int* bucket_arr = (unsigned int*)alloc((size_t)nb * CAPB * 4);
    int* col_src = (int*)alloc((size_t)nb * CAPB * 4);
    float* el    = (float*)alloc((size_t)n * HGAT * 4);
    float* er    = (float*)alloc((size_t)n * HGAT * 4);
    unsigned short* featb = (unsigned short*)alloc((size_t)n * DIMGAT * 2);
    unsigned short* Wb    = (unsigned short*)alloc((size_t)DIMGAT * DIMGAT * 2);
    float* out   = (float*)d_out;

    // ---- CSR build (shared by both layers) ----
    initb_kernel<<<(nb + 255) / 256, 256, 0, stream>>>(bcursor, nb);
    bucket_scatter<<<(e + 4095) / 4096, 256, 0, stream>>>(src, dst, bcursor,
                                                          bucket_arr, e, nb);
    bucket_finalize<<<nb, 256, 0, stream>>>(bucket_arr, bcursor, col_src,
                                            start, deg, n);

    const int gemm_grid = 1024;
    const int elr_grid  = (n * HGAT + 255) / 256;
    const int agg_grid  = (n * 64 + 255) / 256;

    // ---- layer 0 ----
    wcvt_kernel<<<8, 256, 0, stream>>>(W0, Wb);
    gemm_mfma_kernel<<<gemm_grid, 256, 0, stream>>>(n_feat, Wb, featb, n);
    elr_kernel<<<elr_grid, 256, 0, stream>>>(featb, al0, ar0, el, er, n);
    agg_kernel<<<agg_grid, 256, 0, stream>>>(featb, el, er, col_src, start, deg,
                                             n_feat, b0, out, n, 1);
    // ---- layer 1 (h1 lives in d_out; in-place residual read is per-node safe) ----
    wcvt_kernel<<<8, 256, 0, stream>>>(W1, Wb);
    gemm_mfma_kernel<<<gemm_grid, 256, 0, stream>>>(out, Wb, featb, n);
    elr_kernel<<<elr_grid, 256, 0, stream>>>(featb, al1, ar1, el, er, n);
    agg_kernel<<<agg_grid, 256, 0, stream>>>(featb, el, er, col_src, start, deg,
                                             out, b1, out, n, 0);
}